// Round 7
// baseline (69.455 us; speedup 1.0000x reference)
//
#include <hip/hip_runtime.h>
#include <hip/hip_bf16.h>

// Problem constants (B=1, S=5, Q=512, T=64, D=2048)
#define S_DIM 5
#define Q_DIM 512
#define T_DIM 64
#define D_DIM 2048
#define EPS_CS 1e-8f

typedef float f32x4 __attribute__((ext_vector_type(4)));

// Workspace layout (float words):
//   sp      : [S_DIM][D_DIM] @ 0       (10240)
//   snpart  : [S_DIM][8]     @ 10240   (40)
//   num     : [Q_DIM][8]     @ 10280   (4096)  6 used per q
//   qcnt    : uint[Q_DIM]    @ 14376   (512)
//   loss    : float          @ 14888
//   losscnt : uint           @ 14889
#define WS_SP      0
#define WS_SNPART  10240
#define WS_NUM     10280
#define WS_QCNT    14376
#define WS_LOSS    14888
#define WS_LOSSCNT 14889
#define WS_ZERO_BASE 10280
#define WS_ZERO_LEN  4610   // num + qcnt + loss + losscnt

__device__ __forceinline__ float wave_reduce_sum(float v) {
    #pragma unroll
    for (int off = 32; off > 0; off >>= 1)
        v += __shfl_down(v, off, 64);
    return v;
}

__device__ __forceinline__ float dot4(f32x4 a, f32x4 b) {
    return a.x * b.x + a.y * b.y + a.z * b.z + a.w * b.w;
}

// Kernel 1: pool supp over T -> sp[s][d] (+ per-(s,chunk) sum-of-squares).
// Also zero-inits all accumulator/counter words for K2 (visibility via
// kernel-boundary release). 40 blocks x 512 threads; block = (s, c).
__global__ __launch_bounds__(512) void supp_pool_kernel(
    const float* __restrict__ supp, float* __restrict__ ws)
{
    float* sp     = ws + WS_SP;
    float* snpart = ws + WS_SNPART;

    const int gid = blockIdx.x * 512 + threadIdx.x;
    if (gid < WS_ZERO_LEN) ws[WS_ZERO_BASE + gid] = 0.0f;

    const int s    = blockIdx.x >> 3;
    const int c    = blockIdx.x & 7;
    const int tg   = threadIdx.x >> 6;   // 8 t-groups
    const int lane = threadIdx.x & 63;
    const int slot = c * 64 + lane;      // f32x4 slot in [0, 512)

    const f32x4* base = (const f32x4*)(supp + (size_t)s * T_DIM * D_DIM);

    f32x4 acc = {0.f, 0.f, 0.f, 0.f};
    #pragma unroll
    for (int i = 0; i < 8; ++i) {
        const int t = tg * 8 + i;
        acc += base[t * (D_DIM / 4) + slot];
    }

    __shared__ f32x4 lds[8][64];
    lds[tg][lane] = acc;
    __syncthreads();
    if (tg == 0) {
        f32x4 tot = lds[0][lane];
        #pragma unroll
        for (int w = 1; w < 8; ++w) tot += lds[w][lane];
        tot *= (1.0f / (float)T_DIM);
        ((f32x4*)(sp + (size_t)s * D_DIM))[slot] = tot;

        float sq = wave_reduce_sum(dot4(tot, tot));
        if (lane == 0) snpart[s * 8 + c] = sq;
    }
}

// Kernel 2: 1024 blocks x 512 threads, full 32-waves/CU occupancy.
// Block (q, h) pools D-half h of query row q over T (t-split across two
// 256-thread groups, combined in LDS), computes 6 partial dots, and merges
// them into num[q][*] with relaxed LLC atomics. The second block of each q
// to arrive computes dist / (1-dist) output row / nll; the 512th q to
// finish writes out[0] = mean(nll). All atomics relaxed (no fences).
__global__ __launch_bounds__(512, 8) void query_fused_kernel(
    const float* __restrict__ query, const int* __restrict__ ys,
    float* __restrict__ out, float* __restrict__ ws)
{
    const float* sp     = ws + WS_SP;
    const float* snpart = ws + WS_SNPART;
    float* num          = ws + WS_NUM;
    unsigned int* qcnt  = (unsigned int*)(ws + WS_QCNT);
    float* loss_acc     = ws + WS_LOSS;
    unsigned int* lcnt  = (unsigned int*)(ws + WS_LOSSCNT);

    const int q    = blockIdx.x >> 1;
    const int h    = blockIdx.x & 1;
    const int tid  = threadIdx.x;
    const int tg   = tid >> 8;          // t-half: 0 or 1
    const int sIdx = tid & 255;         // slot within D-half
    const int slot = h * 256 + sIdx;    // f32x4 slot in [0, 512)

    const f32x4* base = (const f32x4*)(query + (size_t)q * T_DIM * D_DIM) + slot;

    f32x4 acc = {0.f, 0.f, 0.f, 0.f};
    const int t0 = tg * 32;
    #pragma unroll 4
    for (int t = t0; t < t0 + 32; ++t)
        acc += base[(size_t)t * (D_DIM / 4)];

    __shared__ f32x4 comb[256];
    __shared__ float lds2[4][6];
    if (tg == 1) comb[sIdx] = acc;
    __syncthreads();

    if (tg == 0) {
        acc = (acc + comb[sIdx]) * (1.0f / (float)T_DIM);

        float vals[6];
        vals[5] = dot4(acc, acc);
        #pragma unroll
        for (int s = 0; s < S_DIM; ++s) {
            f32x4 sv = ((const f32x4*)(sp + (size_t)s * D_DIM))[slot];
            vals[s] = dot4(acc, sv);
        }

        const int wave = tid >> 6;      // 0..3 within tg0
        const int lane = tid & 63;
        #pragma unroll
        for (int k = 0; k < 6; ++k) {
            float r = wave_reduce_sum(vals[k]);
            if (lane == 0) lds2[wave][k] = r;
        }
    }
    __syncthreads();

    if (tid == 0) {
        float part[6], olds[6];
        #pragma unroll
        for (int k = 0; k < 6; ++k) {
            float t = 0.f;
            #pragma unroll
            for (int w = 0; w < 4; ++w) t += lds2[w][k];
            part[k] = t;
            olds[k] = atomicAdd(&num[(size_t)q * 8 + k], t);
        }
        // Consume returned values: forces the 6 loss-of-partials adds to
        // have completed at the coherence point before the counter RMW.
        __asm__ __volatile__("" :: "v"(olds[0]), "v"(olds[1]), "v"(olds[2]),
                                   "v"(olds[3]), "v"(olds[4]), "v"(olds[5])
                                : "memory");

        unsigned int arrived = atomicAdd(&qcnt[q], 1u);
        if (arrived == 1u) {   // second block of this q: both halves merged
            float tot[6];
            #pragma unroll
            for (int k = 0; k < 6; ++k)
                tot[k] = atomicAdd(&num[(size_t)q * 8 + k], 0.0f);

            const float qn = sqrtf(tot[5]);

            float dist[S_DIM];
            #pragma unroll
            for (int s = 0; s < S_DIM; ++s) {
                float sn2 = 0.f;
                #pragma unroll
                for (int c = 0; c < 8; ++c) sn2 += snpart[s * 8 + c];
                const float sn = sqrtf(sn2);
                const float d  = tot[s] / fmaxf(qn * sn, EPS_CS);
                dist[s] = d;
                out[1 + (size_t)q * S_DIM + s] = 1.0f - d;
            }

            float m = dist[0];
            #pragma unroll
            for (int s = 1; s < S_DIM; ++s) m = fmaxf(m, dist[s]);
            float sum = 0.f;
            #pragma unroll
            for (int s = 0; s < S_DIM; ++s) sum += expf(dist[s] - m);
            const float lse = m + logf(sum);

            int y = ys[q];
            if (y < 0) y = 0;
            if (y >= S_DIM) y = S_DIM - 1;
            const float nll = lse - dist[y];

            float oldl = atomicAdd(loss_acc, nll);
            __asm__ __volatile__("" :: "v"(oldl) : "memory");

            unsigned int done = atomicAdd(lcnt, 1u);
            if (done == Q_DIM - 1) {
                float tot_loss = atomicAdd(loss_acc, 0.0f);
                out[0] = tot_loss * (1.0f / (float)Q_DIM);
            }
        }
    }
}

extern "C" void kernel_launch(void* const* d_in, const int* in_sizes, int n_in,
                              void* d_out, int out_size, void* d_ws, size_t ws_size,
                              hipStream_t stream) {
    const float* supp  = (const float*)d_in[0];
    const float* query = (const float*)d_in[1];
    const int*   ys    = (const int*)d_in[2];
    float* out = (float*)d_out;
    float* ws  = (float*)d_ws;

    supp_pool_kernel<<<S_DIM * 8, 512, 0, stream>>>(supp, ws);
    query_fused_kernel<<<Q_DIM * 2, 512, 0, stream>>>(query, ys, out, ws);
}

// Round 8
// 61.027 us; speedup vs baseline: 1.1381x; 1.1381x over previous
//
#include <hip/hip_runtime.h>
#include <hip/hip_bf16.h>

// Problem constants (B=1, S=5, Q=512, T=64, D=2048)
#define S_DIM 5
#define Q_DIM 512
#define T_DIM 64
#define D_DIM 2048
#define EPS_CS 1e-8f

typedef float f32x4 __attribute__((ext_vector_type(4)));

// Workspace layout (float words):
//   sp      : [S_DIM][D_DIM] @ 0       (10240)
//   snpart  : [S_DIM][8]     @ 10240   (40)
//   num     : [Q_DIM][8]     @ 10280   (4096)  6 used per q
//   qcnt    : uint[Q_DIM]    @ 14376   (512)
//   loss    : float          @ 14888
//   losscnt : uint           @ 14889
#define WS_SP      0
#define WS_SNPART  10240
#define WS_NUM     10280
#define WS_QCNT    14376
#define WS_LOSS    14888
#define WS_LOSSCNT 14889
#define WS_ZERO_BASE 10280
#define WS_ZERO_LEN  4610   // num + qcnt + loss + losscnt

__device__ __forceinline__ float wave_reduce_sum(float v) {
    #pragma unroll
    for (int off = 32; off > 0; off >>= 1)
        v += __shfl_down(v, off, 64);
    return v;
}

__device__ __forceinline__ float dot4(f32x4 a, f32x4 b) {
    return a.x * b.x + a.y * b.y + a.z * b.z + a.w * b.w;
}

// Kernel 1: pool supp over T -> sp[s][d] (+ per-(s,chunk) sum-of-squares).
// Also zero-inits all accumulator/counter words for K2 (visibility via
// kernel-boundary release). 40 blocks x 512 threads; block = (s, c).
__global__ __launch_bounds__(512) void supp_pool_kernel(
    const float* __restrict__ supp, float* __restrict__ ws)
{
    float* sp     = ws + WS_SP;
    float* snpart = ws + WS_SNPART;

    const int gid = blockIdx.x * 512 + threadIdx.x;
    if (gid < WS_ZERO_LEN) ws[WS_ZERO_BASE + gid] = 0.0f;

    const int s    = blockIdx.x >> 3;
    const int c    = blockIdx.x & 7;
    const int tg   = threadIdx.x >> 6;   // 8 t-groups
    const int lane = threadIdx.x & 63;
    const int slot = c * 64 + lane;      // f32x4 slot in [0, 512)

    const f32x4* base = (const f32x4*)(supp + (size_t)s * T_DIM * D_DIM);

    f32x4 acc = {0.f, 0.f, 0.f, 0.f};
    #pragma unroll
    for (int i = 0; i < 8; ++i) {
        const int t = tg * 8 + i;
        acc += base[t * (D_DIM / 4) + slot];
    }

    __shared__ f32x4 lds[8][64];
    lds[tg][lane] = acc;
    __syncthreads();
    if (tg == 0) {
        f32x4 tot = lds[0][lane];
        #pragma unroll
        for (int w = 1; w < 8; ++w) tot += lds[w][lane];
        tot *= (1.0f / (float)T_DIM);
        ((f32x4*)(sp + (size_t)s * D_DIM))[slot] = tot;

        float sq = wave_reduce_sum(dot4(tot, tot));
        if (lane == 0) snpart[s * 8 + c] = sq;
    }
}

// Kernel 2: 2048 blocks x 256 threads = 8 blocks/CU x 4 waves = 32 waves/CU
// (full occupancy), lean registers (no spill risk under the 64-VGPR cap).
// Block (q, c) owns D-quarter c of query row q: two 128-thread t-groups
// accumulate t=0..31 / t=32..63, combine via one 2 KB LDS pass, dot vs the
// 5 sp quarter-rows + self-dot (D-split keeps the self-dot decomposable),
// then merge 6 partials into num[q][*] with relaxed LLC atomics. The 4th
// arriving block of each q computes dist / (1-dist) row / nll; the 512th
// finished q writes out[0] = mean(nll). No fences anywhere.
__global__ __launch_bounds__(256, 8) void query_fused_kernel(
    const float* __restrict__ query, const int* __restrict__ ys,
    float* __restrict__ out, float* __restrict__ ws)
{
    const float* sp     = ws + WS_SP;
    const float* snpart = ws + WS_SNPART;
    float* num          = ws + WS_NUM;
    unsigned int* qcnt  = (unsigned int*)(ws + WS_QCNT);
    float* loss_acc     = ws + WS_LOSS;
    unsigned int* lcnt  = (unsigned int*)(ws + WS_LOSSCNT);

    const int q    = blockIdx.x >> 2;
    const int c    = blockIdx.x & 3;
    const int tid  = threadIdx.x;
    const int tg   = tid >> 7;          // t-half: 0 or 1
    const int sIdx = tid & 127;         // slot within D-quarter
    const int slot = c * 128 + sIdx;    // f32x4 slot in [0, 512)

    const f32x4* base = (const f32x4*)(query + (size_t)q * T_DIM * D_DIM) + slot;

    f32x4 acc = {0.f, 0.f, 0.f, 0.f};
    const int t0 = tg * 32;
    #pragma unroll 8
    for (int t = t0; t < t0 + 32; ++t)
        acc += base[(size_t)t * (D_DIM / 4)];

    __shared__ f32x4 comb[128];
    __shared__ float lds2[2][6];
    if (tg == 1) comb[sIdx] = acc;
    __syncthreads();

    if (tg == 0) {
        acc = (acc + comb[sIdx]) * (1.0f / (float)T_DIM);

        float vals[6];
        vals[5] = dot4(acc, acc);
        #pragma unroll
        for (int s = 0; s < S_DIM; ++s) {
            f32x4 sv = ((const f32x4*)(sp + (size_t)s * D_DIM))[slot];
            vals[s] = dot4(acc, sv);
        }

        const int wave = tid >> 6;      // 0..1 within tg0
        const int lane = tid & 63;
        #pragma unroll
        for (int k = 0; k < 6; ++k) {
            float r = wave_reduce_sum(vals[k]);
            if (lane == 0) lds2[wave][k] = r;
        }
    }
    __syncthreads();

    if (tid == 0) {
        float olds[6];
        #pragma unroll
        for (int k = 0; k < 6; ++k) {
            float t = lds2[0][k] + lds2[1][k];
            olds[k] = atomicAdd(&num[(size_t)q * 8 + k], t);
        }
        // Consume returned values: the 6 partial adds have completed at the
        // coherence point before the counter RMW below issues.
        __asm__ __volatile__("" :: "v"(olds[0]), "v"(olds[1]), "v"(olds[2]),
                                   "v"(olds[3]), "v"(olds[4]), "v"(olds[5])
                                : "memory");

        unsigned int arrived = atomicAdd(&qcnt[q], 1u);
        if (arrived == 3u) {   // 4th quarter of this q: all partials merged
            float tot[6];
            #pragma unroll
            for (int k = 0; k < 6; ++k)
                tot[k] = atomicAdd(&num[(size_t)q * 8 + k], 0.0f);

            const float qn = sqrtf(tot[5]);

            float dist[S_DIM];
            #pragma unroll
            for (int s = 0; s < S_DIM; ++s) {
                float sn2 = 0.f;
                #pragma unroll
                for (int cc = 0; cc < 8; ++cc) sn2 += snpart[s * 8 + cc];
                const float sn = sqrtf(sn2);
                const float d  = tot[s] / fmaxf(qn * sn, EPS_CS);
                dist[s] = d;
                out[1 + (size_t)q * S_DIM + s] = 1.0f - d;
            }

            float m = dist[0];
            #pragma unroll
            for (int s = 1; s < S_DIM; ++s) m = fmaxf(m, dist[s]);
            float sum = 0.f;
            #pragma unroll
            for (int s = 0; s < S_DIM; ++s) sum += expf(dist[s] - m);
            const float lse = m + logf(sum);

            int y = ys[q];
            if (y < 0) y = 0;
            if (y >= S_DIM) y = S_DIM - 1;
            const float nll = lse - dist[y];

            float oldl = atomicAdd(loss_acc, nll);
            __asm__ __volatile__("" :: "v"(oldl) : "memory");

            unsigned int done = atomicAdd(lcnt, 1u);
            if (done == Q_DIM - 1) {
                float tot_loss = atomicAdd(loss_acc, 0.0f);
                out[0] = tot_loss * (1.0f / (float)Q_DIM);
            }
        }
    }
}

extern "C" void kernel_launch(void* const* d_in, const int* in_sizes, int n_in,
                              void* d_out, int out_size, void* d_ws, size_t ws_size,
                              hipStream_t stream) {
    const float* supp  = (const float*)d_in[0];
    const float* query = (const float*)d_in[1];
    const int*   ys    = (const int*)d_in[2];
    float* out = (float*)d_out;
    float* ws  = (float*)d_ws;

    supp_pool_kernel<<<S_DIM * 8, 512, 0, stream>>>(supp, ws);
    query_fused_kernel<<<Q_DIM * 4, 256, 0, stream>>>(query, ys, out, ws);
}